// Round 4
// baseline (54.376 us; speedup 1.0000x reference)
//
#include <hip/hip_runtime.h>

#define TT 4096
#define DD 64
#define NCH2 128
#define CS2 32   // TT / NCH2

// ws layout (in floats)
#define Q_OFF    0
#define K_OFF    (TT*DD)                    // 262144
#define Z_OFF    (K_OFF + 4*TT*DD)          // 1310720
#define CSUM_OFF (Z_OFF + 8*TT*DD)          // 3407872  (8*NCH2*DD = 65536)
#define T_OFF    (CSUM_OFF + 8*NCH2*DD)     // 3473408  (4*TT = 16384) ~14 MB total

// ---------------------------------------------------------------------------
// Kernel 1: five MLPs + fused chunk-sums.
// Block = 1024 threads (16 waves) over a 64-row tile; wave w owns dims
// [4w,4w+4). h is ROW-major in LDS with a 16B XOR swizzle
// (slot = k4 ^ (row&7)) so each thread's 4-k fragment is ONE ds_read_b128
// at the 8-cycle conflict-free floor (vs 4x ds_read_b32 before).
// Weights: wave-uniform float4 loads (scalarizable). After the last layer
// (q>=1) each thread holds K[row][4w..4w+4); a 5-round __shfl_xor butterfly
// produces per-32-row half-chunk sums of K_j[d]*V_j[c] -> csum at NCH2=128
// granularity, V columns cached in LDS during the tile load. t-values
// extracted for free from the tile load.
// ---------------------------------------------------------------------------
__global__ __launch_bounds__(1024) void mlp_kernel(
    const float* __restrict__ x1, const float* __restrict__ x2,
    const float* __restrict__ x3, const float* __restrict__ x4,
    const float* __restrict__ Wq_w, const float* __restrict__ Wq_b,
    const float* __restrict__ Wk_w, const float* __restrict__ Wk_b,
    float* __restrict__ ws)
{
    const int q    = blockIdx.x >> 6;    // 0 = Q-mlp, 1..4 = K-mlp (m = q-1)
    const int br   = blockIdx.x & 63;    // row block (= chunk)
    const int lane = threadIdx.x & 63;   // row within tile
    const int w    = threadIdx.x >> 6;   // dim-group 0..15

    const float* x; const float* W; const float* B; float* out;
    if (q == 0) { x = x1; W = Wq_w; B = Wq_b; out = ws + Q_OFF; }
    else {
        const int m = q - 1;
        x = (m == 0) ? x1 : (m == 1) ? x2 : (m == 2) ? x3 : x4;
        W = Wk_w + m * 3 * DD * DD;
        B = Wk_b + m * 3 * DD;
        out = ws + K_OFF + m * TT * DD;
    }

    __shared__ float h[DD * DD];   // h[row][slot], slot = k4 ^ (row&7), 16B units
    __shared__ float vb[2 * DD];   // V columns 0,1 for this tile

    // coalesced tile load: 1024 float4
    {
        const float4 v = reinterpret_cast<const float4*>(x + br * 64 * DD)[threadIdx.x];
        const int e   = threadIdx.x * 4;
        const int row = e >> 6;
        const int k0  = e & 63;
        const int slot = ((k0 >> 2) ^ (row & 7)) << 2;
        *reinterpret_cast<float4*>(&h[row * 64 + slot]) = v;
        if (k0 == 0)  { vb[row] = v.x; vb[DD + row] = v.y; }
        if (q >= 1 && k0 == 60) ws[T_OFF + (q - 1) * TT + br * 64 + row] = v.w;
    }

    const int dofs = __builtin_amdgcn_readfirstlane(4 * w);
    const int rx   = lane & 7;

    float a0, a1, a2, a3;
    for (int L = 0; L < 3; ++L) {
        __syncthreads();
        const float* WL = W + L * DD * DD + dofs;
        const float4 bv = *reinterpret_cast<const float4*>(B + L * DD + dofs);
        a0 = bv.x; a1 = bv.y; a2 = bv.z; a3 = bv.w;

        #pragma unroll 4
        for (int k4 = 0; k4 < 16; ++k4) {
            const float4 hv = *reinterpret_cast<const float4*>(&h[lane * 64 + ((k4 ^ rx) << 2)]);
            const float4 w0 = *reinterpret_cast<const float4*>(WL + (4 * k4 + 0) * DD);
            const float4 w1 = *reinterpret_cast<const float4*>(WL + (4 * k4 + 1) * DD);
            const float4 w2 = *reinterpret_cast<const float4*>(WL + (4 * k4 + 2) * DD);
            const float4 w3 = *reinterpret_cast<const float4*>(WL + (4 * k4 + 3) * DD);
            a0 += hv.x * w0.x; a1 += hv.x * w0.y; a2 += hv.x * w0.z; a3 += hv.x * w0.w;
            a0 += hv.y * w1.x; a1 += hv.y * w1.y; a2 += hv.y * w1.z; a3 += hv.y * w1.w;
            a0 += hv.z * w2.x; a1 += hv.z * w2.y; a2 += hv.z * w2.z; a3 += hv.z * w2.w;
            a0 += hv.w * w3.x; a1 += hv.w * w3.y; a2 += hv.w * w3.z; a3 += hv.w * w3.w;
        }

        if (L < 2) {
            a0 = fmaxf(a0, 0.f); a1 = fmaxf(a1, 0.f);
            a2 = fmaxf(a2, 0.f); a3 = fmaxf(a3, 0.f);
            __syncthreads();
            const int slot = (w ^ rx) << 2;   // dofs>>2 == w
            *reinterpret_cast<float4*>(&h[lane * 64 + slot]) = make_float4(a0, a1, a2, a3);
        }
    }

    // write result rows
    {
        float* o = out + (br * 64 + lane) * DD + dofs;
        *reinterpret_cast<float4*>(o) = make_float4(a0, a1, a2, a3);
    }

    // fused half-chunk sums (K-mlps only)
    if (q >= 1) {
        const int m = q - 1;
        const float v0 = vb[lane], v1 = vb[DD + lane];
        float p00 = a0 * v0, p01 = a1 * v0, p02 = a2 * v0, p03 = a3 * v0;
        float p10 = a0 * v1, p11 = a1 * v1, p12 = a2 * v1, p13 = a3 * v1;
        #pragma unroll
        for (int off = 1; off <= 16; off <<= 1) {
            p00 += __shfl_xor(p00, off); p01 += __shfl_xor(p01, off);
            p02 += __shfl_xor(p02, off); p03 += __shfl_xor(p03, off);
            p10 += __shfl_xor(p10, off); p11 += __shfl_xor(p11, off);
            p12 += __shfl_xor(p12, off); p13 += __shfl_xor(p13, off);
        }
        if ((lane & 31) == 0) {
            const int ch2 = br * 2 + (lane >> 5);
            float* c0 = ws + CSUM_OFF + ((m * 2 + 0) * NCH2 + ch2) * DD + dofs;
            float* c1 = ws + CSUM_OFF + ((m * 2 + 1) * NCH2 + ch2) * DD + dofs;
            c0[0] = p00; c0[1] = p01; c0[2] = p02; c0[3] = p03;
            c1[0] = p10; c1[1] = p11; c1[2] = p12; c1[3] = p13;
        }
    }
}

// ---------------------------------------------------------------------------
// Kernel 2: inclusive prefix Z[mc][j][d]. One wave per (mc, ch2), CS2=32.
// Chunk-prefix fold = one burst of 127 unconditional coalesced loads + select.
// ---------------------------------------------------------------------------
__global__ __launch_bounds__(64) void zfill_kernel(
    const float* __restrict__ x1, const float* __restrict__ x2,
    const float* __restrict__ x3, const float* __restrict__ x4,
    float* __restrict__ ws)
{
    const int mc  = blockIdx.x >> 7;   // m*2 + c
    const int ch2 = blockIdx.x & 127;
    const int m   = mc >> 1;
    const int c   = mc & 1;
    const int d   = threadIdx.x;
    const float* xm = (m == 0) ? x1 : (m == 1) ? x2 : (m == 2) ? x3 : x4;
    const float* K = ws + K_OFF + m * TT * DD;
    const float* csum = ws + CSUM_OFF + mc * NCH2 * DD;
    float* Z = ws + Z_OFF + mc * TT * DD;

    float r = 0.f;
    #pragma unroll
    for (int cc = 0; cc < NCH2 - 1; ++cc) {
        const float v = csum[cc * DD + d];
        r += (cc < ch2) ? v : 0.f;
    }

    const int j0 = ch2 * CS2;
    #pragma unroll 8
    for (int jj = 0; jj < CS2; ++jj) {
        const int j = j0 + jj;
        r += K[j * DD + d] * xm[j * DD + c];
        Z[j * DD + d] = r;
    }
}

// ---------------------------------------------------------------------------
// Kernel 3: wave-per-row output. 4 binary searches interleaved (independent
// chains) on dense t-arrays, then out_i = Q_i . Z[p-1], 64-lane shuffle reduce.
// ---------------------------------------------------------------------------
__global__ __launch_bounds__(256) void gather_kernel(
    const float* __restrict__ ws, float* __restrict__ out)
{
    const int lane = threadIdx.x & 63;
    const int wid  = threadIdx.x >> 6;
    const int i = blockIdx.x * 4 + wid;

    const float* Q  = ws + Q_OFF;
    const float* Z  = ws + Z_OFF;
    const float* tb = ws + T_OFF;

    const float t1i = tb[0 * TT + i];
    const float qd  = Q[i * DD + lane];

    int lo[4] = {0, 0, 0, 0};
    int hi[4] = {TT, TT, TT, TT};
    #pragma unroll
    for (int s = 0; s < 13; ++s) {
        #pragma unroll
        for (int m = 0; m < 4; ++m) {
            if (lo[m] < hi[m]) {
                const int mid = (lo[m] + hi[m]) >> 1;
                const bool le = tb[m * TT + mid] <= t1i;
                lo[m] = le ? mid + 1 : lo[m];
                hi[m] = le ? hi[m] : mid;
            }
        }
    }

    float a0 = 0.f, a1 = 0.f;
    #pragma unroll
    for (int m = 0; m < 4; ++m) {
        if (lo[m] > 0) {
            const int p = lo[m] - 1;
            a0 += qd * Z[((m * 2 + 0) * TT + p) * DD + lane];
            a1 += qd * Z[((m * 2 + 1) * TT + p) * DD + lane];
        }
    }

    #pragma unroll
    for (int off = 32; off > 0; off >>= 1) {
        a0 += __shfl_xor(a0, off);
        a1 += __shfl_xor(a1, off);
    }
    if (lane == 0) {
        out[i * 2 + 0] = a0;
        out[i * 2 + 1] = a1;
    }
}

extern "C" void kernel_launch(void* const* d_in, const int* in_sizes, int n_in,
                              void* d_out, int out_size, void* d_ws, size_t ws_size,
                              hipStream_t stream)
{
    const float* x1   = (const float*)d_in[0];
    const float* x2   = (const float*)d_in[1];
    const float* x3   = (const float*)d_in[2];
    const float* x4   = (const float*)d_in[3];
    const float* Wq_w = (const float*)d_in[4];
    const float* Wq_b = (const float*)d_in[5];
    const float* Wk_w = (const float*)d_in[6];
    const float* Wk_b = (const float*)d_in[7];
    float* out = (float*)d_out;
    float* ws  = (float*)d_ws;

    hipLaunchKernelGGL(mlp_kernel,   dim3(5 * 64), dim3(1024), 0, stream,
                       x1, x2, x3, x4, Wq_w, Wq_b, Wk_w, Wk_b, ws);
    hipLaunchKernelGGL(zfill_kernel, dim3(8 * NCH2), dim3(64), 0, stream,
                       x1, x2, x3, x4, ws);
    hipLaunchKernelGGL(gather_kernel, dim3(TT / 4), dim3(256), 0, stream,
                       ws, out);
}

// Round 5
// 51.268 us; speedup vs baseline: 1.0606x; 1.0606x over previous
//
#include <hip/hip_runtime.h>

#define TT 4096
#define DD 64
#define NCH2 128
#define CS2 32   // TT / NCH2

// ws layout (in floats)
#define Q_OFF    0
#define K_OFF    (TT*DD)                    // 262144
#define Z_OFF    (K_OFF + 4*TT*DD)          // 1310720
#define CSUM_OFF (Z_OFF + 8*TT*DD)          // 3407872  (8*NCH2*DD = 65536)
#define T_OFF    (CSUM_OFF + 8*NCH2*DD)     // 3473408  (4*TT = 16384) ~14 MB total

// ---------------------------------------------------------------------------
// Kernel 1: five MLPs + fused half-chunk sums.
// Block = 512 threads (8 waves) per 64-row tile; lane = row; wave w owns
// dims [8w, 8w+8).  KEY CHANGE vs r4: h lives in REGISTERS (float h[64],
// static indexing via full unroll) — the inner k-loop is pure v_fmac with
// SGPR weight operands (wave-uniform readfirstlane'd pointer -> s_load on
// the scalar pipe).  LDS is touched only at layer boundaries (2 writes +
// 16 reads of b128 per wave per layer, 16B-XOR swizzled => conflict-free),
// cutting per-CU LDS traffic ~14x vs r4's in-loop h reads.
// ---------------------------------------------------------------------------
__global__ __launch_bounds__(512, 4) void mlp_kernel(
    const float* __restrict__ x1, const float* __restrict__ x2,
    const float* __restrict__ x3, const float* __restrict__ x4,
    const float* __restrict__ Wq_w, const float* __restrict__ Wq_b,
    const float* __restrict__ Wk_w, const float* __restrict__ Wk_b,
    float* __restrict__ ws)
{
    const int q    = blockIdx.x >> 6;    // 0 = Q-mlp, 1..4 = K-mlp (m = q-1)
    const int br   = blockIdx.x & 63;    // row block (= chunk)
    const int lane = threadIdx.x & 63;   // row within tile
    const int w    = threadIdx.x >> 6;   // dim-group 0..7

    const float* x; const float* W; const float* B; float* out;
    if (q == 0) { x = x1; W = Wq_w; B = Wq_b; out = ws + Q_OFF; }
    else {
        const int m = q - 1;
        x = (m == 0) ? x1 : (m == 1) ? x2 : (m == 2) ? x3 : x4;
        W = Wk_w + m * 3 * DD * DD;
        B = Wk_b + m * 3 * DD;
        out = ws + K_OFF + m * TT * DD;
    }

    __shared__ float hs[DD * DD];   // hs[row*64 + ((g ^ (row&7))<<2) + j], g=16B granule
    __shared__ float vb[2 * DD];    // V columns 0,1 of this tile

    // coalesced tile load: 2 float4 per thread
    {
        const float4* xv = reinterpret_cast<const float4*>(x + br * 64 * DD);
        #pragma unroll
        for (int half = 0; half < 2; ++half) {
            const int idx = threadIdx.x + half * 512;
            const float4 v = xv[idx];
            const int e   = idx * 4;
            const int row = e >> 6;
            const int k0  = e & 63;
            const int slot = ((k0 >> 2) ^ (row & 7)) << 2;
            *reinterpret_cast<float4*>(&hs[row * 64 + slot]) = v;
            if (k0 == 0)  { vb[row] = v.x; vb[DD + row] = v.y; }
            if (q >= 1 && k0 == 60) ws[T_OFF + (q - 1) * TT + br * 64 + row] = v.w;
        }
    }

    const int dofs = __builtin_amdgcn_readfirstlane(8 * w);
    const int r3   = lane & 7;

    float h[DD];
    float a[8];

    for (int L = 0; L < 3; ++L) {
        __syncthreads();   // hs for this layer fully written

        // LDS -> registers: 16 conflict-free ds_read_b128
        #pragma unroll
        for (int g = 0; g < 16; ++g) {
            const float4 hv = *reinterpret_cast<const float4*>(&hs[lane * 64 + ((g ^ r3) << 2)]);
            h[4*g + 0] = hv.x; h[4*g + 1] = hv.y;
            h[4*g + 2] = hv.z; h[4*g + 3] = hv.w;
        }

        const float* WL = W + L * DD * DD + dofs;   // wave-uniform -> s_load
        const float* BL = B + L * DD + dofs;
        {
            const float4 b0 = *reinterpret_cast<const float4*>(BL);
            const float4 b1 = *reinterpret_cast<const float4*>(BL + 4);
            a[0] = b0.x; a[1] = b0.y; a[2] = b0.z; a[3] = b0.w;
            a[4] = b1.x; a[5] = b1.y; a[6] = b1.z; a[7] = b1.w;
        }

        #pragma unroll
        for (int k = 0; k < DD; ++k) {
            const float hk = h[k];
            const float4 wa = *reinterpret_cast<const float4*>(WL + k * DD);
            const float4 wb = *reinterpret_cast<const float4*>(WL + k * DD + 4);
            a[0] += hk * wa.x; a[1] += hk * wa.y; a[2] += hk * wa.z; a[3] += hk * wa.w;
            a[4] += hk * wb.x; a[5] += hk * wb.y; a[6] += hk * wb.z; a[7] += hk * wb.w;
        }

        if (L < 2) {
            #pragma unroll
            for (int j = 0; j < 8; ++j) a[j] = fmaxf(a[j], 0.f);
            __syncthreads();   // all waves done reading hs before overwrite
            const int g0 = 2 * w;     // dofs>>2
            *reinterpret_cast<float4*>(&hs[lane * 64 + ((g0 ^ r3) << 2)]) =
                make_float4(a[0], a[1], a[2], a[3]);
            *reinterpret_cast<float4*>(&hs[lane * 64 + (((g0 + 1) ^ r3) << 2)]) =
                make_float4(a[4], a[5], a[6], a[7]);
        }
    }

    // write result rows
    {
        float* o = out + (br * 64 + lane) * DD + dofs;
        *reinterpret_cast<float4*>(o)     = make_float4(a[0], a[1], a[2], a[3]);
        *reinterpret_cast<float4*>(o + 4) = make_float4(a[4], a[5], a[6], a[7]);
    }

    // fused half-chunk sums (K-mlps only): csum[mc][ch2][d] over 32-row halves
    if (q >= 1) {
        const int m = q - 1;
        const float v0 = vb[lane], v1 = vb[DD + lane];
        float p0[8], p1[8];
        #pragma unroll
        for (int j = 0; j < 8; ++j) { p0[j] = a[j] * v0; p1[j] = a[j] * v1; }
        #pragma unroll
        for (int off = 1; off <= 16; off <<= 1) {
            #pragma unroll
            for (int j = 0; j < 8; ++j) {
                p0[j] += __shfl_xor(p0[j], off);
                p1[j] += __shfl_xor(p1[j], off);
            }
        }
        if ((lane & 31) == 0) {
            const int ch2 = br * 2 + (lane >> 5);
            float* c0 = ws + CSUM_OFF + ((m * 2 + 0) * NCH2 + ch2) * DD + dofs;
            float* c1 = ws + CSUM_OFF + ((m * 2 + 1) * NCH2 + ch2) * DD + dofs;
            #pragma unroll
            for (int j = 0; j < 8; ++j) { c0[j] = p0[j]; c1[j] = p1[j]; }
        }
    }
}

// ---------------------------------------------------------------------------
// Kernel 2: inclusive prefix Z[mc][j][d]. One wave per (mc, ch2), CS2=32.
// Chunk-prefix fold = one burst of 127 unconditional coalesced loads + select.
// ---------------------------------------------------------------------------
__global__ __launch_bounds__(64) void zfill_kernel(
    const float* __restrict__ x1, const float* __restrict__ x2,
    const float* __restrict__ x3, const float* __restrict__ x4,
    float* __restrict__ ws)
{
    const int mc  = blockIdx.x >> 7;   // m*2 + c
    const int ch2 = blockIdx.x & 127;
    const int m   = mc >> 1;
    const int c   = mc & 1;
    const int d   = threadIdx.x;
    const float* xm = (m == 0) ? x1 : (m == 1) ? x2 : (m == 2) ? x3 : x4;
    const float* K = ws + K_OFF + m * TT * DD;
    const float* csum = ws + CSUM_OFF + mc * NCH2 * DD;
    float* Z = ws + Z_OFF + mc * TT * DD;

    float r = 0.f;
    #pragma unroll
    for (int cc = 0; cc < NCH2 - 1; ++cc) {
        const float v = csum[cc * DD + d];
        r += (cc < ch2) ? v : 0.f;
    }

    const int j0 = ch2 * CS2;
    #pragma unroll 8
    for (int jj = 0; jj < CS2; ++jj) {
        const int j = j0 + jj;
        r += K[j * DD + d] * xm[j * DD + c];
        Z[j * DD + d] = r;
    }
}

// ---------------------------------------------------------------------------
// Kernel 3: wave-per-row output. 4 binary searches interleaved (independent
// chains) on dense t-arrays, then out_i = Q_i . Z[p-1], 64-lane shuffle reduce.
// ---------------------------------------------------------------------------
__global__ __launch_bounds__(256) void gather_kernel(
    const float* __restrict__ ws, float* __restrict__ out)
{
    const int lane = threadIdx.x & 63;
    const int wid  = threadIdx.x >> 6;
    const int i = blockIdx.x * 4 + wid;

    const float* Q  = ws + Q_OFF;
    const float* Z  = ws + Z_OFF;
    const float* tb = ws + T_OFF;

    const float t1i = tb[0 * TT + i];
    const float qd  = Q[i * DD + lane];

    int lo[4] = {0, 0, 0, 0};
    int hi[4] = {TT, TT, TT, TT};
    #pragma unroll
    for (int s = 0; s < 13; ++s) {
        #pragma unroll
        for (int m = 0; m < 4; ++m) {
            if (lo[m] < hi[m]) {
                const int mid = (lo[m] + hi[m]) >> 1;
                const bool le = tb[m * TT + mid] <= t1i;
                lo[m] = le ? mid + 1 : lo[m];
                hi[m] = le ? hi[m] : mid;
            }
        }
    }

    float a0 = 0.f, a1 = 0.f;
    #pragma unroll
    for (int m = 0; m < 4; ++m) {
        if (lo[m] > 0) {
            const int p = lo[m] - 1;
            a0 += qd * Z[((m * 2 + 0) * TT + p) * DD + lane];
            a1 += qd * Z[((m * 2 + 1) * TT + p) * DD + lane];
        }
    }

    #pragma unroll
    for (int off = 32; off > 0; off >>= 1) {
        a0 += __shfl_xor(a0, off);
        a1 += __shfl_xor(a1, off);
    }
    if (lane == 0) {
        out[i * 2 + 0] = a0;
        out[i * 2 + 1] = a1;
    }
}

extern "C" void kernel_launch(void* const* d_in, const int* in_sizes, int n_in,
                              void* d_out, int out_size, void* d_ws, size_t ws_size,
                              hipStream_t stream)
{
    const float* x1   = (const float*)d_in[0];
    const float* x2   = (const float*)d_in[1];
    const float* x3   = (const float*)d_in[2];
    const float* x4   = (const float*)d_in[3];
    const float* Wq_w = (const float*)d_in[4];
    const float* Wq_b = (const float*)d_in[5];
    const float* Wk_w = (const float*)d_in[6];
    const float* Wk_b = (const float*)d_in[7];
    float* out = (float*)d_out;
    float* ws  = (float*)d_ws;

    hipLaunchKernelGGL(mlp_kernel,   dim3(5 * 64), dim3(512), 0, stream,
                       x1, x2, x3, x4, Wq_w, Wq_b, Wk_w, Wk_b, ws);
    hipLaunchKernelGGL(zfill_kernel, dim3(8 * NCH2), dim3(64), 0, stream,
                       x1, x2, x3, x4, ws);
    hipLaunchKernelGGL(gather_kernel, dim3(TT / 4), dim3(256), 0, stream,
                       ws, out);
}